// Round 5
// baseline (182.321 us; speedup 1.0000x reference)
//
#include <hip/hip_runtime.h>
#include <math.h>

// Problem constants (from reference)
#define NB 320
#define NAC 5
#define NH 26
#define NW 26
#define CHW 676                    // NH*NW
#define KTOT 3380                  // NAC*CHW (divisible by 4)
#define BSTRIDE 20280              // 30*CHW floats per batch image
#define MAXB 50
#define CS 20
#define NMETA 20
#define DWROWS 64
#define DWDIM 1024
#define NPAIR (NMETA * NMETA)
#define NCBLK 4                    // cell blocks per batch (1024 cells each)
#define GX (NCBLK + 1)             // + 1 boxes block per batch
#define NFUSED (NB * GX)           // 1600
#define NSAME NMETA                // 20 same-term blocks
#define TOTB (NFUSED + NSAME + NPAIR)   // 2020 blocks total
#define NPART (NFUSED + NSAME)     // 1620 loss partials

__constant__ float c_aw[5] = {1.3221f, 3.19275f, 5.05587f, 9.47112f, 11.2364f};
__constant__ float c_ah[5] = {1.73145f, 4.00944f, 8.09892f, 4.84053f, 10.0071f};

// wave-uniform register broadcast (box data lives in lane l's registers)
__device__ __forceinline__ float rl_f(float v, int l) {
    return __int_as_float(__builtin_amdgcn_readlane(__float_as_int(v), l));
}

// ---------------------------------------------------------------------------
// ONE kernel, 1D grid of 2020 blocks x 256:
//   [0,1600)     : region loss — per batch b=gid/5: sub=gid%5<4 -> cells path
//                  (4 cells/thread, fma-max silence loop), sub==4 -> boxes path
//                  (scatter-winner dedup + override/class corrections).
//   [1600,1620)  : same-term per class (ssq - cnt*e^2 over that class's rows).
//   [1620,2020)  : pairwise enews distance, enews recomputed inline from dw
//                  (no cross-block dependency).
// Last-arriving block (counter) computes dmin, sums partials, writes loss[0].
// ---------------------------------------------------------------------------
__global__ __launch_bounds__(256) void mega_k(const float* __restrict__ out,
                                              const float* __restrict__ target,
                                              const float* __restrict__ dw,
                                              const int* __restrict__ ids,
                                              float* __restrict__ part,
                                              float* __restrict__ dmat,
                                              unsigned* __restrict__ counter,
                                              float* __restrict__ loss) {
    __shared__ float sred[4];
    __shared__ bool slast;
    __shared__ int scnt[NMETA];
    __shared__ float sdd;

    int gid = blockIdx.x;
    int tid = threadIdx.x;
    int lane = tid & 63;
    int wid = tid >> 6;

    if (gid < NFUSED) {
        // =============== region-loss path ===============
        int b = gid / GX;
        int sub = gid - b * GX;

        // per-lane box setup: lane t (t<50) holds box t of batch b
        float blox = 1e30f, bhix = -1e30f, bloy = 1e30f, bhiy = -1e30f, bneg = 0.0f;
        float gx = 0.0f, gy = 0.0f, gw = 0.0f, gh = 0.0f;
        bool bvalid;
        {
            int t = (lane < MAXB) ? lane : 0;
            const float* g = target + b * (MAXB * 5) + t * 5;
            float g1 = g[1];
            gx = g1 * (float)NW;
            gy = g[2] * (float)NH;
            gw = g[3] * (float)NW;
            gh = g[4] * (float)NH;
            bvalid = (g1 != 0.0f) && (lane < MAXB);
            if (bvalid) {
                blox = gx - 0.5f * gw; bhix = gx + 0.5f * gw;
                bloy = gy - 0.5f * gh; bhiy = gy + 0.5f * gh;
                bneg = 0.375f * gw * gh;   // ta; silent <=> inter - ta > thr
            }
        }

        if (sub < NCBLK) {
            // ---------- cells path: 4 consecutive cells per thread ----------
            int k0 = sub * 1024 + tid * 4;
            float contrib = 0.0f;
            if (k0 < KTOT) {
                int a = k0 / CHW;
                int rem0 = k0 - a * CHW;          // never straddles an anchor plane
                const float* base = out + (size_t)b * BSTRIDE + a * 6 * CHW + rem0;
                float4 R0 = *(const float4*)(base + 0 * CHW);
                float4 R1 = *(const float4*)(base + 1 * CHW);
                float4 R2 = *(const float4*)(base + 2 * CHW);
                float4 R3 = *(const float4*)(base + 3 * CHW);
                float4 R4 = *(const float4*)(base + 4 * CHW);
                float RX[4] = {R0.x, R0.y, R0.z, R0.w};
                float RY[4] = {R1.x, R1.y, R1.z, R1.w};
                float RW[4] = {R2.x, R2.y, R2.z, R2.w};
                float RH[4] = {R3.x, R3.y, R3.z, R3.w};
                float RC[4] = {R4.x, R4.y, R4.z, R4.w};
                float X[4], Y[4], CF[4];
                float PLOX[4], PHIX[4], PLOY[4], PHIY[4], THR[4], SM[4];
                float aw = c_aw[a], ah = c_ah[a];
#pragma unroll
                for (int c = 0; c < 4; c++) {
                    int rem = rem0 + c;
                    int i = rem / NW;
                    int j = rem - i * NW;
                    float x = 1.0f / (1.0f + __expf(-RX[c]));
                    float y = 1.0f / (1.0f + __expf(-RY[c]));
                    float conf = 1.0f / (1.0f + __expf(-RC[c]));
                    float pw = __expf(RW[c]) * aw;
                    float ph = __expf(RH[c]) * ah;
                    float px = x + (float)j;
                    float py = y + (float)i;
                    PLOX[c] = px - 0.5f * pw; PHIX[c] = px + 0.5f * pw;
                    PLOY[c] = py - 0.5f * ph; PHIY[c] = py + 0.5f * ph;
                    THR[c] = 0.375f * (pw * ph);
                    SM[c] = -1e30f;
                    X[c] = x; Y[c] = y; CF[c] = conf;
                }
#pragma unroll 5
                for (int tb = 0; tb < MAXB; tb++) {
                    float thix = rl_f(bhix, tb), tlox = rl_f(blox, tb);
                    float thiy = rl_f(bhiy, tb), tloy = rl_f(bloy, tb);
                    float ta   = rl_f(bneg, tb);
#pragma unroll
                    for (int c = 0; c < 4; c++) {
                        float ix = fminf(PHIX[c], thix) - fmaxf(PLOX[c], tlox);
                        float iy = fminf(PHIY[c], thiy) - fmaxf(PLOY[c], tloy);
                        float ixc = fmaxf(ix, 0.0f), iyc = fmaxf(iy, 0.0f);
                        SM[c] = fmaxf(SM[c], __builtin_fmaf(ixc, iyc, -ta));
                    }
                }
#pragma unroll
                for (int c = 0; c < 4; c++) {
                    float dx = X[c] - 0.5f, dy = Y[c] - 0.5f;
                    contrib += 0.5f * (dx * dx + dy * dy + RW[c] * RW[c] + RH[c] * RH[c]);
                    if (!(SM[c] > THR[c])) contrib += 0.5f * CF[c] * CF[c];
                }
            }
#pragma unroll
            for (int o = 32; o > 0; o >>= 1) contrib += __shfl_down(contrib, o, 64);
            if (lane == 0) sred[wid] = contrib;
            __syncthreads();
            if (tid == 0) {
                float tot = sred[0] + sred[1] + sred[2] + sred[3];
                __hip_atomic_store(&part[gid], tot, __ATOMIC_RELEASE, __HIP_MEMORY_SCOPE_AGENT);
            }
        } else {
            // ---------- boxes path: single wave ----------
            if (tid < 64) {
                int t = lane;
                int fidx = -1 - t;      // unique sentinel for invalid boxes
                int bn = 0, gi = 0, gj = 0;
                if (bvalid) {
                    float area = gw * gh;
                    float best = -1.0f;
#pragma unroll
                    for (int n = 0; n < 5; n++) {
                        float inter = fminf(gw, c_aw[n]) * fminf(gh, c_ah[n]);
                        float iou = inter / (area + c_aw[n] * c_ah[n] - inter);
                        if (iou > best) { best = iou; bn = n; }   // first max wins
                    }
                    gi = min(max((int)gx, 0), NW - 1);  // trunc == astype(int32)
                    gj = min(max((int)gy, 0), NH - 1);
                    fidx = (bn * NH + gj) * NW + gi;
                }
                // winner iff no larger t' maps to the same cell (last-write-wins)
                bool winner = bvalid;
                for (int t2 = 1; t2 < MAXB; t2++) {
                    int f2 = __builtin_amdgcn_readlane(fidx, t2);
                    winner = winner && ((t2 <= t) || (f2 != fidx));
                }
                float contrib = 0.0f;
                if (winner) {
                    int rem = gj * NW + gi;
                    const float* cell = out + (size_t)b * BSTRIDE + bn * 6 * CHW + rem;
                    float rx = cell[0 * CHW];
                    float ry = cell[1 * CHW];
                    float w  = cell[2 * CHW];
                    float h  = cell[3 * CHW];
                    float rc = cell[4 * CHW];
                    float x = 1.0f / (1.0f + __expf(-rx));
                    float y = 1.0f / (1.0f + __expf(-ry));
                    float conf = 1.0f / (1.0f + __expf(-rc));
                    float aw = c_aw[bn], ah = c_ah[bn];
                    float pw = __expf(w) * aw;
                    float ph = __expf(h) * ah;
                    float px = x + (float)gi;
                    float py = y + (float)gj;
                    float plox = px - 0.5f * pw, phix = px + 0.5f * pw;
                    float ploy = py - 0.5f * ph, phiy = py + 0.5f * ph;
                    float parea = pw * ph;
                    float thr = 0.375f * parea;
                    float smax = -1e30f;
                    for (int tb = 0; tb < MAXB; tb++) {
                        float thix = rl_f(bhix, tb), tlox = rl_f(blox, tb);
                        float thiy = rl_f(bhiy, tb), tloy = rl_f(bloy, tb);
                        float ta   = rl_f(bneg, tb);
                        float ix = fminf(phix, thix) - fmaxf(plox, tlox);
                        float iy = fminf(phiy, thiy) - fmaxf(ploy, tloy);
                        smax = fmaxf(smax, __builtin_fmaf(fmaxf(ix, 0.0f), fmaxf(iy, 0.0f), -ta));
                    }
                    bool silent = smax > thr;
                    float dx0 = x - 0.5f, dy0 = y - 0.5f;
                    float basel = 0.5f * (dx0 * dx0 + dy0 * dy0 + w * w + h * h);
                    if (!silent) basel += 0.5f * conf * conf;
                    // iou_gt with own box (this lane's registers)
                    float ix = fminf(phix, bhix) - fmaxf(plox, blox);
                    float iy = fminf(phiy, bhiy) - fmaxf(ploy, bloy);
                    float inter = fmaxf(ix, 0.0f) * fmaxf(iy, 0.0f);
                    float iou = inter / (parea + gw * gh - inter);
                    float txv = gx - (float)gi, tyv = gy - (float)gj;
                    float twv = __logf(gw / aw), thv = __logf(gh / ah);
                    float dx = x - txv, dy = y - tyv;
                    float dwv = w - twv, dhv = h - thv;
                    float dc = conf - iou;
                    float ovr = 0.5f * (dx * dx + dy * dy + dwv * dwv + dhv * dhv) + 2.5f * dc * dc;
                    // class log-softmax over the CS=20 images of this chunk
                    int bs = b / CS, cs = b - bs * CS;
                    const float* cl = out + (size_t)(bs * CS) * BSTRIDE + (bn * 6 + 5) * CHW + rem;
                    float v[CS];
                    float m = -1e30f;
#pragma unroll
                    for (int c2 = 0; c2 < CS; c2++) { v[c2] = cl[(size_t)c2 * BSTRIDE]; m = fmaxf(m, v[c2]); }
                    float s = 0.0f, own = 0.0f;
#pragma unroll
                    for (int c2 = 0; c2 < CS; c2++) {
                        s += __expf(v[c2] - m);
                        if (c2 == cs) own = v[c2];
                    }
                    contrib = ovr - basel + (m + __logf(s)) - own;
                }
#pragma unroll
                for (int o = 32; o > 0; o >>= 1) contrib += __shfl_down(contrib, o, 64);
                if (tid == 0)
                    __hip_atomic_store(&part[gid], contrib, __ATOMIC_RELEASE, __HIP_MEMORY_SCOPE_AGENT);
            }
        }
    } else if (gid < NFUSED + NSAME) {
        // =============== same-term per class ===============
        int c = gid - NFUSED;
        float acc[4] = {0, 0, 0, 0}, ssq[4] = {0, 0, 0, 0};
        int cnt = 0;
        for (int r = 0; r < DWROWS; r++) {
            int idr = ids[r];                 // uniform scalar load + uniform branch
            if (idr == c) {
                cnt++;
#pragma unroll
                for (int k = 0; k < 4; k++) {
                    float v = dw[r * DWDIM + tid + k * 256];
                    acc[k] += v; ssq[k] += v * v;
                }
            }
        }
        float same = 0.0f;
        if (cnt > 0) {
            float inv = 1.0f / (float)cnt;
#pragma unroll
            for (int k = 0; k < 4; k++) {
                float e = acc[k] * inv;
                same += ssq[k] - (float)cnt * e * e;
            }
        }
#pragma unroll
        for (int o = 32; o > 0; o >>= 1) same += __shfl_down(same, o, 64);
        if (lane == 0) sred[wid] = same;
        __syncthreads();
        if (tid == 0) {
            float tot = sred[0] + sred[1] + sred[2] + sred[3];
            __hip_atomic_store(&part[gid], tot, __ATOMIC_RELEASE, __HIP_MEMORY_SCOPE_AGENT);
        }
    } else {
        // =============== pairwise enews distance (enews inline) ===============
        int p = gid - NFUSED - NSAME;
        int pi = p / NMETA, pj = p - pi * NMETA;
        float s = 0.0f;
        if (pi != pj) {
            float ai[4] = {0, 0, 0, 0}, aj[4] = {0, 0, 0, 0};
            int ci = 0, cj = 0;
            for (int r = 0; r < DWROWS; r++) {
                int idr = ids[r];             // uniform branches
                if (idr == pi) {
                    ci++;
#pragma unroll
                    for (int k = 0; k < 4; k++) ai[k] += dw[r * DWDIM + tid + k * 256];
                } else if (idr == pj) {
                    cj++;
#pragma unroll
                    for (int k = 0; k < 4; k++) aj[k] += dw[r * DWDIM + tid + k * 256];
                }
            }
            float ii = 1.0f / fmaxf((float)ci, 1.0f);
            float ij = 1.0f / fmaxf((float)cj, 1.0f);
#pragma unroll
            for (int k = 0; k < 4; k++) {
                float df = ai[k] * ii - aj[k] * ij;
                s += df * df;
            }
        }
#pragma unroll
        for (int o = 32; o > 0; o >>= 1) s += __shfl_down(s, o, 64);
        if (lane == 0) sred[wid] = s;
        __syncthreads();
        if (tid == 0) {
            float tot = sred[0] + sred[1] + sred[2] + sred[3];
            __hip_atomic_store(&dmat[p], tot, __ATOMIC_RELEASE, __HIP_MEMORY_SCOPE_AGENT);
        }
    }

    // =============== common epilogue: last-arriving block finishes ===============
    if (tid == 0) {
        unsigned prev = __hip_atomic_fetch_add(counter, 1u, __ATOMIC_ACQ_REL, __HIP_MEMORY_SCOPE_AGENT);
        slast = (prev == TOTB - 1);
    }
    __syncthreads();
    if (!slast) return;

    if (tid < NMETA) {
        int c = 0;
        for (int r = 0; r < DWROWS; r++) c += (ids[r] == tid) ? 1 : 0;
        scnt[tid] = c;
    }
    __syncthreads();
    float dd = 0.0f;
    if (tid < NMETA && scnt[tid] > 0) {
        float dmin = INFINITY;
        bool any = false;
        for (int j = 0; j < NMETA; j++) {
            if (j != tid && scnt[j] > 0) {
                any = true;
                float dv = __hip_atomic_load(&dmat[tid * NMETA + j], __ATOMIC_ACQUIRE, __HIP_MEMORY_SCOPE_AGENT);
                dmin = fminf(dmin, dv);
            }
        }
        dd = any ? dmin : 0.0f;
    }
    if (tid < 64) {
#pragma unroll
        for (int o = 32; o > 0; o >>= 1) dd += __shfl_down(dd, o, 64);
        if (tid == 0) sdd = dd;
    }
    float ps = 0.0f;
    for (int i2 = tid; i2 < NPART; i2 += 256)
        ps += __hip_atomic_load(&part[i2], __ATOMIC_ACQUIRE, __HIP_MEMORY_SCOPE_AGENT);
#pragma unroll
    for (int o = 32; o > 0; o >>= 1) ps += __shfl_down(ps, o, 64);
    if (lane == 0) sred[wid] = ps;
    __syncthreads();
    if (tid == 0) loss[0] = (sred[0] + sred[1] + sred[2] + sred[3]) - sdd;
}

// ---------------------------------------------------------------------------
extern "C" void kernel_launch(void* const* d_in, const int* in_sizes, int n_in,
                              void* d_out, int out_size, void* d_ws, size_t ws_size,
                              hipStream_t stream) {
    const float* output = (const float*)d_in[0];   // (320, 30, 26, 26)
    const float* target = (const float*)d_in[1];   // (16, 20, 250) == (320, 50, 5)
    const float* dw     = (const float*)d_in[2];   // (1, 64, 1024)
    const int*   ids    = (const int*)d_in[3];     // (64,)
    float* loss = (float*)d_out;

    float* part = (float*)d_ws;                    // 1620 loss partials
    float* dmat = part + NPART;                    // 400 pair distances
    unsigned* counter = (unsigned*)(dmat + NPAIR); // arrival counter

    hipMemsetAsync(counter, 0, sizeof(unsigned), stream);
    mega_k<<<TOTB, 256, 0, stream>>>(output, target, dw, ids, part, dmat, counter, loss);
}

// Round 6
// 125.130 us; speedup vs baseline: 1.4570x; 1.4570x over previous
//
#include <hip/hip_runtime.h>
#include <math.h>

// Problem constants (from reference)
#define NB 320
#define NAC 5
#define NH 26
#define NW 26
#define CHW 676                    // NH*NW
#define KTOT 3380                  // NAC*CHW (divisible by 4)
#define BSTRIDE 20280              // 30*CHW floats per batch image
#define MAXB 50
#define CS 20
#define NMETA 20
#define DWROWS 64
#define DWDIM 1024
#define NPAIR (NMETA * NMETA)
#define NCBLK 4                    // cell blocks per batch, 1024 cells each
#define GX (NCBLK + 1)             // + 1 boxes block
#define NPART (NB * GX)            // 1600 fused partials
#define NPART2 (NMETA * 4)         // 80 meta1 partials

__constant__ float c_aw[5] = {1.3221f, 3.19275f, 5.05587f, 9.47112f, 11.2364f};
__constant__ float c_ah[5] = {1.73145f, 4.00944f, 8.09892f, 4.84053f, 10.0071f};

// wave-uniform register broadcast (box data lives in lane l's registers)
__device__ __forceinline__ float rl_f(float v, int l) {
    return __int_as_float(__builtin_amdgcn_readlane(__float_as_int(v), l));
}

// ---------------------------------------------------------------------------
// Fused kernel. Grid (5, 320) x 256. Plain part[] stores; ordering between
// kernels comes from same-stream kernel boundaries (R4-proven; device-scope
// release/acquire per block measured ~55us slower in R5).
//   blockIdx.x < 4 : cells path — 4 cells/thread (float4 plane loads),
//                    fma-max silence loop, readlane broadcasts amortized 4x.
//   blockIdx.x == 4: boxes path (wave 0) — scatter-winner dedup (max t =
//                    numpy last-write-wins) + override/class corrections.
// ---------------------------------------------------------------------------
__global__ __launch_bounds__(256) void fused_k(const float* __restrict__ out,
                                               const float* __restrict__ target,
                                               float* __restrict__ part,
                                               unsigned* __restrict__ counter) {
    int b = blockIdx.y;
    int tid = threadIdx.x;
    int lane = tid & 63;
    int bid = b * GX + blockIdx.x;

    // per-lane box setup: lane t (t<50) holds box t of batch b
    float blox = 1e30f, bhix = -1e30f, bloy = 1e30f, bhiy = -1e30f, bta = 0.0f;
    float gx = 0.0f, gy = 0.0f, gw = 0.0f, gh = 0.0f;
    bool bvalid;
    {
        int t = (lane < MAXB) ? lane : 0;
        const float* g = target + b * (MAXB * 5) + t * 5;
        float g1 = g[1];
        gx = g1 * (float)NW;
        gy = g[2] * (float)NH;
        gw = g[3] * (float)NW;
        gh = g[4] * (float)NH;
        bvalid = (g1 != 0.0f) && (lane < MAXB);
        if (bvalid) {
            blox = gx - 0.5f * gw; bhix = gx + 0.5f * gw;
            bloy = gy - 0.5f * gh; bhiy = gy + 0.5f * gh;
            bta = 0.375f * gw * gh;    // silent <=> inter - ta > 0.375*parea
        }
    }

    if (blockIdx.x < NCBLK) {
        // ------------------------- cells path -------------------------
        __shared__ float sred[4];
        int k0 = blockIdx.x * 1024 + tid * 4;     // 4 consecutive cells
        float contrib = 0.0f;
        if (k0 < KTOT) {
            int a = k0 / CHW;
            int rem0 = k0 - a * CHW;              // never straddles an anchor plane
            const float* base = out + (size_t)b * BSTRIDE + a * 6 * CHW + rem0;
            float4 R0 = *(const float4*)(base + 0 * CHW);
            float4 R1 = *(const float4*)(base + 1 * CHW);
            float4 R2 = *(const float4*)(base + 2 * CHW);
            float4 R3 = *(const float4*)(base + 3 * CHW);
            float4 R4 = *(const float4*)(base + 4 * CHW);
            float RX[4] = {R0.x, R0.y, R0.z, R0.w};
            float RY[4] = {R1.x, R1.y, R1.z, R1.w};
            float RW[4] = {R2.x, R2.y, R2.z, R2.w};
            float RH[4] = {R3.x, R3.y, R3.z, R3.w};
            float RC[4] = {R4.x, R4.y, R4.z, R4.w};
            float X[4], Y[4], CF[4];
            float PLOX[4], PHIX[4], PLOY[4], PHIY[4], THR[4], SM[4];
            float aw = c_aw[a], ah = c_ah[a];
#pragma unroll
            for (int c = 0; c < 4; c++) {
                int rem = rem0 + c;
                int i = rem / NW;
                int j = rem - i * NW;
                float x = 1.0f / (1.0f + __expf(-RX[c]));
                float y = 1.0f / (1.0f + __expf(-RY[c]));
                float conf = 1.0f / (1.0f + __expf(-RC[c]));
                float pw = __expf(RW[c]) * aw;
                float ph = __expf(RH[c]) * ah;
                float px = x + (float)j;
                float py = y + (float)i;
                PLOX[c] = px - 0.5f * pw; PHIX[c] = px + 0.5f * pw;
                PLOY[c] = py - 0.5f * ph; PHIY[c] = py + 0.5f * ph;
                THR[c] = 0.375f * (pw * ph);
                SM[c] = -1e30f;
                X[c] = x; Y[c] = y; CF[c] = conf;
            }
            // fma-max silence loop: 10 VALU per cell per box + 5 readlanes,
            // unroll 10 -> 50 readlanes batched per body for latency hiding
#pragma unroll 10
            for (int tb = 0; tb < MAXB; tb++) {
                float thix = rl_f(bhix, tb), tlox = rl_f(blox, tb);
                float thiy = rl_f(bhiy, tb), tloy = rl_f(bloy, tb);
                float ta   = rl_f(bta, tb);
#pragma unroll
                for (int c = 0; c < 4; c++) {
                    float ix = fminf(PHIX[c], thix) - fmaxf(PLOX[c], tlox);
                    float iy = fminf(PHIY[c], thiy) - fmaxf(PLOY[c], tloy);
                    float ixc = fmaxf(ix, 0.0f), iyc = fmaxf(iy, 0.0f);
                    SM[c] = fmaxf(SM[c], __builtin_fmaf(ixc, iyc, -ta));
                }
            }
#pragma unroll
            for (int c = 0; c < 4; c++) {
                float dx = X[c] - 0.5f, dy = Y[c] - 0.5f;
                contrib += 0.5f * (dx * dx + dy * dy + RW[c] * RW[c] + RH[c] * RH[c]);
                if (!(SM[c] > THR[c])) contrib += 0.5f * CF[c] * CF[c];
            }
        }
#pragma unroll
        for (int o = 32; o > 0; o >>= 1) contrib += __shfl_down(contrib, o, 64);
        int wid = tid >> 6;
        if (lane == 0) sred[wid] = contrib;
        __syncthreads();
        if (tid == 0) part[bid] = sred[0] + sred[1] + sred[2] + sred[3];
    } else {
        // ------------------------- boxes path -------------------------
        if (tid >= 64) return;  // single wave
        if (b == 0 && tid == 0)
            __hip_atomic_store(counter, 0u, __ATOMIC_RELAXED, __HIP_MEMORY_SCOPE_AGENT);
        int t = lane;
        int fidx = -1 - t;      // unique sentinel for invalid boxes
        int bn = 0, gi = 0, gj = 0;
        if (bvalid) {
            float area = gw * gh;
            float best = -1.0f;
#pragma unroll
            for (int n = 0; n < 5; n++) {
                float inter = fminf(gw, c_aw[n]) * fminf(gh, c_ah[n]);
                float iou = inter / (area + c_aw[n] * c_ah[n] - inter);
                if (iou > best) { best = iou; bn = n; }   // first max wins
            }
            gi = min(max((int)gx, 0), NW - 1);  // trunc == astype(int32), vals >= 0
            gj = min(max((int)gy, 0), NH - 1);
            fidx = (bn * NH + gj) * NW + gi;
        }
        // winner iff no larger t' maps to the same cell (last-write-wins)
        bool winner = bvalid;
        for (int t2 = 1; t2 < MAXB; t2++) {
            int f2 = __builtin_amdgcn_readlane(fidx, t2);
            winner = winner && ((t2 <= t) || (f2 != fidx));
        }
        float contrib = 0.0f;
        if (winner) {
            int rem = gj * NW + gi;
            const float* cell = out + (size_t)b * BSTRIDE + bn * 6 * CHW + rem;
            float rx = cell[0 * CHW];
            float ry = cell[1 * CHW];
            float w  = cell[2 * CHW];
            float h  = cell[3 * CHW];
            float rc = cell[4 * CHW];
            float x = 1.0f / (1.0f + __expf(-rx));
            float y = 1.0f / (1.0f + __expf(-ry));
            float conf = 1.0f / (1.0f + __expf(-rc));
            float aw = c_aw[bn], ah = c_ah[bn];
            float pw = __expf(w) * aw;
            float ph = __expf(h) * ah;
            float px = x + (float)gi;
            float py = y + (float)gj;
            float plox = px - 0.5f * pw, phix = px + 0.5f * pw;
            float ploy = py - 0.5f * ph, phiy = py + 0.5f * ph;
            float parea = pw * ph;
            float thr = 0.375f * parea;
            float smax = -1e30f;
            for (int tb = 0; tb < MAXB; tb++) {
                float thix = rl_f(bhix, tb), tlox = rl_f(blox, tb);
                float thiy = rl_f(bhiy, tb), tloy = rl_f(bloy, tb);
                float ta   = rl_f(bta, tb);
                float ix = fminf(phix, thix) - fmaxf(plox, tlox);
                float iy = fminf(phiy, thiy) - fmaxf(ploy, tloy);
                smax = fmaxf(smax, __builtin_fmaf(fmaxf(ix, 0.0f), fmaxf(iy, 0.0f), -ta));
            }
            bool silent = smax > thr;
            float dx0 = x - 0.5f, dy0 = y - 0.5f;
            float basel = 0.5f * (dx0 * dx0 + dy0 * dy0 + w * w + h * h);
            if (!silent) basel += 0.5f * conf * conf;
            // iou_gt with own box (this lane's registers)
            float ix = fminf(phix, bhix) - fmaxf(plox, blox);
            float iy = fminf(phiy, bhiy) - fmaxf(ploy, bloy);
            float inter = fmaxf(ix, 0.0f) * fmaxf(iy, 0.0f);
            float iou = inter / (parea + gw * gh - inter);
            float txv = gx - (float)gi, tyv = gy - (float)gj;
            float twv = __logf(gw / aw), thv = __logf(gh / ah);
            float dx = x - txv, dy = y - tyv;
            float dwv = w - twv, dhv = h - thv;
            float dc = conf - iou;
            float ovr = 0.5f * (dx * dx + dy * dy + dwv * dwv + dhv * dhv) + 2.5f * dc * dc;
            // class log-softmax over the CS=20 images of this chunk
            int bs = b / CS, cs = b - bs * CS;
            const float* cl = out + (size_t)(bs * CS) * BSTRIDE + (bn * 6 + 5) * CHW + rem;
            float v[CS];
            float m = -1e30f;
#pragma unroll
            for (int c2 = 0; c2 < CS; c2++) { v[c2] = cl[(size_t)c2 * BSTRIDE]; m = fmaxf(m, v[c2]); }
            float s = 0.0f, own = 0.0f;
#pragma unroll
            for (int c2 = 0; c2 < CS; c2++) {
                s += __expf(v[c2] - m);
                if (c2 == cs) own = v[c2];
            }
            contrib = ovr - basel + (m + __logf(s)) - own;
        }
#pragma unroll
        for (int o = 32; o > 0; o >>= 1) contrib += __shfl_down(contrib, o, 64);
        if (tid == 0) part[bid] = contrib;
    }
}

// ---------------------------------------------------------------------------
// meta1: enews means + same-term in ONE dw pass (sum(v-e)^2 = sum v^2 - cnt e^2).
// Grid (20, 4) x 256 -> part2[80].
// ---------------------------------------------------------------------------
__global__ __launch_bounds__(256) void meta1_k(const float* __restrict__ dw,
                                               const int* __restrict__ ids,
                                               float* __restrict__ enews,
                                               float* __restrict__ part2) {
    __shared__ float sred[4];
    int c = blockIdx.x;
    int d = blockIdx.y * 256 + threadIdx.x;
    float acc = 0.0f, ssq = 0.0f;
    int cnt = 0;
    for (int r = 0; r < DWROWS; r++) {
        int idr = ids[r];                 // uniform -> scalar load
        float v = dw[r * DWDIM + d];
        if (idr == c) { acc += v; ssq += v * v; cnt++; }
    }
    float e = acc / fmaxf((float)cnt, 1.0f);
    enews[c * DWDIM + d] = e;
    float same = ssq - (float)cnt * e * e;
#pragma unroll
    for (int o = 32; o > 0; o >>= 1) same += __shfl_down(same, o, 64);
    int lane = threadIdx.x & 63, wid = threadIdx.x >> 6;
    if (lane == 0) sred[wid] = same;
    __syncthreads();
    if (threadIdx.x == 0) part2[c * 4 + blockIdx.y] = sred[0] + sred[1] + sred[2] + sred[3];
}

// ---------------------------------------------------------------------------
// meta2: 400 blocks compute pairwise enews distances; last-arriving block
// computes dmin, sums ALL partials (part[1600]+part2[80]), writes loss[0].
// ---------------------------------------------------------------------------
__global__ __launch_bounds__(256) void meta2_k(const int* __restrict__ ids,
                                               const float* __restrict__ enews,
                                               float* __restrict__ dmat,
                                               unsigned* __restrict__ counter,
                                               const float* __restrict__ partbuf,
                                               float* __restrict__ loss) {
    __shared__ float sred[4];
    __shared__ bool slast;
    __shared__ int scnt[NMETA];
    __shared__ float sdd;
    int tid = threadIdx.x;
    int p = blockIdx.x;
    int pi = p / NMETA, pj = p - pi * NMETA;
    float s = 0.0f;
    if (pi != pj) {
#pragma unroll
        for (int c = 0; c < 4; c++) {
            int d = tid + c * 256;
            float df = enews[pi * DWDIM + d] - enews[pj * DWDIM + d];
            s += df * df;
        }
    }
#pragma unroll
    for (int o = 32; o > 0; o >>= 1) s += __shfl_down(s, o, 64);
    int lane = tid & 63, wid = tid >> 6;
    if (lane == 0) sred[wid] = s;
    __syncthreads();
    if (tid == 0) {
        float tot = sred[0] + sred[1] + sred[2] + sred[3];
        __hip_atomic_store(&dmat[p], tot, __ATOMIC_RELEASE, __HIP_MEMORY_SCOPE_AGENT);
        unsigned prev = __hip_atomic_fetch_add(counter, 1u, __ATOMIC_ACQ_REL, __HIP_MEMORY_SCOPE_AGENT);
        slast = (prev == NPAIR - 1);
    }
    __syncthreads();
    if (!slast) return;
    // --- final block ---
    if (tid < NMETA) {
        int c = 0;
        for (int r = 0; r < DWROWS; r++) c += (ids[r] == tid) ? 1 : 0;
        scnt[tid] = c;
    }
    __syncthreads();
    float dd = 0.0f;
    if (tid < NMETA && scnt[tid] > 0) {
        float dmin = INFINITY;
        bool any = false;
        for (int j = 0; j < NMETA; j++) {
            if (j != tid && scnt[j] > 0) {
                any = true;
                float dv = __hip_atomic_load(&dmat[tid * NMETA + j], __ATOMIC_ACQUIRE, __HIP_MEMORY_SCOPE_AGENT);
                dmin = fminf(dmin, dv);
            }
        }
        dd = any ? dmin : 0.0f;
    }
    if (tid < 64) {
#pragma unroll
        for (int o = 32; o > 0; o >>= 1) dd += __shfl_down(dd, o, 64);
        if (tid == 0) sdd = dd;
    }
    // sum the 1680 partial losses
    float ps = 0.0f;
    for (int i2 = tid; i2 < NPART + NPART2; i2 += 256) ps += partbuf[i2];
#pragma unroll
    for (int o = 32; o > 0; o >>= 1) ps += __shfl_down(ps, o, 64);
    if (lane == 0) sred[wid] = ps;
    __syncthreads();
    if (tid == 0) loss[0] = (sred[0] + sred[1] + sred[2] + sred[3]) - sdd;
}

// ---------------------------------------------------------------------------
extern "C" void kernel_launch(void* const* d_in, const int* in_sizes, int n_in,
                              void* d_out, int out_size, void* d_ws, size_t ws_size,
                              hipStream_t stream) {
    const float* output = (const float*)d_in[0];   // (320, 30, 26, 26)
    const float* target = (const float*)d_in[1];   // (16, 20, 250) == (320, 50, 5)
    const float* dw     = (const float*)d_in[2];   // (1, 64, 1024)
    const int*   ids    = (const int*)d_in[3];     // (64,)
    float* loss = (float*)d_out;

    float* enews = (float*)d_ws;                    // 80 KB
    float* dmat  = enews + NMETA * DWDIM;           // 1.6 KB
    float* part  = dmat + NPAIR;                    // 1600 floats (fused partials)
    float* part2 = part + NPART;                    // 80 floats (meta1 partials)
    unsigned* counter = (unsigned*)(part2 + NPART2);

    dim3 grid(GX, NB);
    fused_k<<<grid, 256, 0, stream>>>(output, target, part, counter);
    dim3 g1(NMETA, DWDIM / 256);
    meta1_k<<<g1, 256, 0, stream>>>(dw, ids, enews, part2);
    meta2_k<<<NPAIR, 256, 0, stream>>>(ids, enews, dmat, counter, part, loss);
}

// Round 7
// 104.411 us; speedup vs baseline: 1.7462x; 1.1984x over previous
//
#include <hip/hip_runtime.h>
#include <math.h>

// Problem constants (from reference)
#define NB 320
#define NAC 5
#define NH 26
#define NW 26
#define CHW 676                    // NH*NW
#define KTOT 3380                  // NAC*CHW (divisible by 4)
#define BSTRIDE 20280              // 30*CHW floats per batch image
#define MAXB 50
#define CS 20
#define NMETA 20
#define DWROWS 64
#define DWDIM 1024
#define NPAIR (NMETA * NMETA)
#define NCBLK 4                    // cell blocks per batch, 1024 cells each
#define NPARTR (NB * NCBLK)        // 1280 region partials
#define NMETAY ((NSAMEPAIR + NCBLK - 1) / NCBLK)
#define NSAMEPAIR (NMETA + NPAIR)  // 420 meta blocks
#define NPART (NPARTR + NMETA)     // 1300 loss partials (region + same-term)

__constant__ float c_aw[5] = {1.3221f, 3.19275f, 5.05587f, 9.47112f, 11.2364f};
__constant__ float c_ah[5] = {1.73145f, 4.00944f, 8.09892f, 4.84053f, 10.0071f};

// wave-uniform register broadcast (box data lives in lane l's registers)
__device__ __forceinline__ float rl_f(float v, int l) {
    return __int_as_float(__builtin_amdgcn_readlane(__float_as_int(v), l));
}

// ---------------------------------------------------------------------------
// Kernel A. Grid (4, 320 + 105) x 256. NO atomics, plain stores only.
//  y < 320:  region loss for batch y. All 4 waves: cells path (4 cells/thread,
//            float4 plane loads, fma-max silence loop with readlane
//            broadcasts). In block x==3 (cells 3072..3379 only), wave 2 has no
//            cells -> it runs the boxes path (scatter-winner dedup = numpy
//            last-write-wins + override/class corrections). One part[] store
//            per block.
//  y >= 320: meta path, p = (y-320)*4 + x in [0,420):
//            p < 20   -> same-term for class p (ssq - cnt*e^2) -> part[1280+p]
//            p >= 20  -> pairwise enews distance, enews recomputed inline from
//                        dw (no cross-block dependency) -> dmat[p-20]
// ---------------------------------------------------------------------------
__global__ __launch_bounds__(256) void fused_k(const float* __restrict__ out,
                                               const float* __restrict__ target,
                                               const float* __restrict__ dw,
                                               const int* __restrict__ ids,
                                               float* __restrict__ part,
                                               float* __restrict__ dmat) {
    __shared__ float sred[4];
    int tid = threadIdx.x;
    int lane = tid & 63;
    int wid = tid >> 6;
    int b = blockIdx.y;

    if (b >= NB) {
        // =============== meta path ===============
        int p = (b - NB) * NCBLK + blockIdx.x;
        float s = 0.0f;
        if (p < NMETA) {
            // same-term for class p: sum(v-e)^2 = ssq - cnt*e^2 over class rows
            int c = p;
            float acc[4] = {0, 0, 0, 0}, ssq[4] = {0, 0, 0, 0};
            int cnt = 0;
            for (int r = 0; r < DWROWS; r++) {
                int idr = ids[r];             // uniform scalar load/branch
                if (idr == c) {
                    cnt++;
#pragma unroll
                    for (int k = 0; k < 4; k++) {
                        float v = dw[r * DWDIM + tid + k * 256];
                        acc[k] += v; ssq[k] += v * v;
                    }
                }
            }
            if (cnt > 0) {
                float inv = 1.0f / (float)cnt;
#pragma unroll
                for (int k = 0; k < 4; k++) {
                    float e = acc[k] * inv;
                    s += ssq[k] - (float)cnt * e * e;
                }
            }
        } else {
            // pairwise distance between class means (inline recompute)
            int pp = p - NMETA;
            int pi = pp / NMETA, pj = pp - pi * NMETA;
            if (pi != pj) {
                float ai[4] = {0, 0, 0, 0}, aj[4] = {0, 0, 0, 0};
                int ci = 0, cj = 0;
                for (int r = 0; r < DWROWS; r++) {
                    int idr = ids[r];
                    if (idr == pi) {
                        ci++;
#pragma unroll
                        for (int k = 0; k < 4; k++) ai[k] += dw[r * DWDIM + tid + k * 256];
                    } else if (idr == pj) {
                        cj++;
#pragma unroll
                        for (int k = 0; k < 4; k++) aj[k] += dw[r * DWDIM + tid + k * 256];
                    }
                }
                float ii = 1.0f / fmaxf((float)ci, 1.0f);
                float ij = 1.0f / fmaxf((float)cj, 1.0f);
#pragma unroll
                for (int k = 0; k < 4; k++) {
                    float df = ai[k] * ii - aj[k] * ij;
                    s += df * df;
                }
            }
        }
#pragma unroll
        for (int o = 32; o > 0; o >>= 1) s += __shfl_down(s, o, 64);
        if (lane == 0) sred[wid] = s;
        __syncthreads();
        if (tid == 0) {
            float tot = sred[0] + sred[1] + sred[2] + sred[3];
            if (p < NMETA) part[NPARTR + p] = tot;
            else dmat[p - NMETA] = tot;
        }
        return;
    }

    // =============== region path (batch b) ===============
    // per-lane box setup: lane t (t<50) of EVERY wave holds box t of batch b
    float blox = 1e30f, bhix = -1e30f, bloy = 1e30f, bhiy = -1e30f, bta = 0.0f;
    float gx = 0.0f, gy = 0.0f, gw = 0.0f, gh = 0.0f;
    bool bvalid;
    {
        int t = (lane < MAXB) ? lane : 0;
        const float* g = target + b * (MAXB * 5) + t * 5;
        float g1 = g[1];
        gx = g1 * (float)NW;
        gy = g[2] * (float)NH;
        gw = g[3] * (float)NW;
        gh = g[4] * (float)NH;
        bvalid = (g1 != 0.0f) && (lane < MAXB);
        if (bvalid) {
            blox = gx - 0.5f * gw; bhix = gx + 0.5f * gw;
            bloy = gy - 0.5f * gh; bhiy = gy + 0.5f * gh;
            bta = 0.375f * gw * gh;    // silent <=> inter - ta > 0.375*parea
        }
    }

    bool isbox = (blockIdx.x == NCBLK - 1) && (wid == 2);  // wave 2 of block 3: no cells
    float contrib = 0.0f;

    if (!isbox) {
        // ---------------- cells path: 4 consecutive cells/thread ----------------
        int k0 = blockIdx.x * 1024 + tid * 4;
        if (k0 < KTOT) {
            int a = k0 / CHW;
            int rem0 = k0 - a * CHW;              // never straddles an anchor plane
            const float* base = out + (size_t)b * BSTRIDE + a * 6 * CHW + rem0;
            float4 R0 = *(const float4*)(base + 0 * CHW);
            float4 R1 = *(const float4*)(base + 1 * CHW);
            float4 R2 = *(const float4*)(base + 2 * CHW);
            float4 R3 = *(const float4*)(base + 3 * CHW);
            float4 R4 = *(const float4*)(base + 4 * CHW);
            float RX[4] = {R0.x, R0.y, R0.z, R0.w};
            float RY[4] = {R1.x, R1.y, R1.z, R1.w};
            float RW[4] = {R2.x, R2.y, R2.z, R2.w};
            float RH[4] = {R3.x, R3.y, R3.z, R3.w};
            float RC[4] = {R4.x, R4.y, R4.z, R4.w};
            float X[4], Y[4], CF[4];
            float PLOX[4], PHIX[4], PLOY[4], PHIY[4], THR[4], SM[4];
            float aw = c_aw[a], ah = c_ah[a];
#pragma unroll
            for (int c = 0; c < 4; c++) {
                int rem = rem0 + c;
                int i = rem / NW;
                int j = rem - i * NW;
                float x = 1.0f / (1.0f + __expf(-RX[c]));
                float y = 1.0f / (1.0f + __expf(-RY[c]));
                float conf = 1.0f / (1.0f + __expf(-RC[c]));
                float pw = __expf(RW[c]) * aw;
                float ph = __expf(RH[c]) * ah;
                float px = x + (float)j;
                float py = y + (float)i;
                PLOX[c] = px - 0.5f * pw; PHIX[c] = px + 0.5f * pw;
                PLOY[c] = py - 0.5f * ph; PHIY[c] = py + 0.5f * ph;
                THR[c] = 0.375f * (pw * ph);
                SM[c] = -1e30f;
                X[c] = x; Y[c] = y; CF[c] = conf;
            }
#pragma unroll 10
            for (int tb = 0; tb < MAXB; tb++) {
                float thix = rl_f(bhix, tb), tlox = rl_f(blox, tb);
                float thiy = rl_f(bhiy, tb), tloy = rl_f(bloy, tb);
                float ta   = rl_f(bta, tb);
#pragma unroll
                for (int c = 0; c < 4; c++) {
                    float ix = fminf(PHIX[c], thix) - fmaxf(PLOX[c], tlox);
                    float iy = fminf(PHIY[c], thiy) - fmaxf(PLOY[c], tloy);
                    float ixc = fmaxf(ix, 0.0f), iyc = fmaxf(iy, 0.0f);
                    SM[c] = fmaxf(SM[c], __builtin_fmaf(ixc, iyc, -ta));
                }
            }
#pragma unroll
            for (int c = 0; c < 4; c++) {
                float dx = X[c] - 0.5f, dy = Y[c] - 0.5f;
                contrib += 0.5f * (dx * dx + dy * dy + RW[c] * RW[c] + RH[c] * RH[c]);
                if (!(SM[c] > THR[c])) contrib += 0.5f * CF[c] * CF[c];
            }
        }
    } else {
        // ---------------- boxes path (one wave, lanes = boxes) ----------------
        int t = lane;
        int fidx = -1 - t;      // unique sentinel for invalid boxes
        int bn = 0, gi = 0, gj = 0;
        if (bvalid) {
            float area = gw * gh;
            float best = -1.0f;
#pragma unroll
            for (int n = 0; n < 5; n++) {
                float inter = fminf(gw, c_aw[n]) * fminf(gh, c_ah[n]);
                float iou = inter / (area + c_aw[n] * c_ah[n] - inter);
                if (iou > best) { best = iou; bn = n; }   // first max wins
            }
            gi = min(max((int)gx, 0), NW - 1);  // trunc == astype(int32), vals >= 0
            gj = min(max((int)gy, 0), NH - 1);
            fidx = (bn * NH + gj) * NW + gi;
        }
        // winner iff no larger t' maps to the same cell (last-write-wins)
        bool winner = bvalid;
        for (int t2 = 1; t2 < MAXB; t2++) {
            int f2 = __builtin_amdgcn_readlane(fidx, t2);
            winner = winner && ((t2 <= t) || (f2 != fidx));
        }
        if (winner) {
            int rem = gj * NW + gi;
            const float* cell = out + (size_t)b * BSTRIDE + bn * 6 * CHW + rem;
            float rx = cell[0 * CHW];
            float ry = cell[1 * CHW];
            float w  = cell[2 * CHW];
            float h  = cell[3 * CHW];
            float rc = cell[4 * CHW];
            float x = 1.0f / (1.0f + __expf(-rx));
            float y = 1.0f / (1.0f + __expf(-ry));
            float conf = 1.0f / (1.0f + __expf(-rc));
            float aw = c_aw[bn], ah = c_ah[bn];
            float pw = __expf(w) * aw;
            float ph = __expf(h) * ah;
            float px = x + (float)gi;
            float py = y + (float)gj;
            float plox = px - 0.5f * pw, phix = px + 0.5f * pw;
            float ploy = py - 0.5f * ph, phiy = py + 0.5f * ph;
            float parea = pw * ph;
            float thr = 0.375f * parea;
            float smax = -1e30f;
            for (int tb = 0; tb < MAXB; tb++) {
                float thix = rl_f(bhix, tb), tlox = rl_f(blox, tb);
                float thiy = rl_f(bhiy, tb), tloy = rl_f(bloy, tb);
                float ta   = rl_f(bta, tb);
                float ix = fminf(phix, thix) - fmaxf(plox, tlox);
                float iy = fminf(phiy, thiy) - fmaxf(ploy, tloy);
                smax = fmaxf(smax, __builtin_fmaf(fmaxf(ix, 0.0f), fmaxf(iy, 0.0f), -ta));
            }
            bool silent = smax > thr;
            float dx0 = x - 0.5f, dy0 = y - 0.5f;
            float basel = 0.5f * (dx0 * dx0 + dy0 * dy0 + w * w + h * h);
            if (!silent) basel += 0.5f * conf * conf;
            // iou_gt with own box (this lane's registers)
            float ix = fminf(phix, bhix) - fmaxf(plox, blox);
            float iy = fminf(phiy, bhiy) - fmaxf(ploy, bloy);
            float inter = fmaxf(ix, 0.0f) * fmaxf(iy, 0.0f);
            float iou = inter / (parea + gw * gh - inter);
            float txv = gx - (float)gi, tyv = gy - (float)gj;
            float twv = __logf(gw / aw), thv = __logf(gh / ah);
            float dx = x - txv, dy = y - tyv;
            float dwv = w - twv, dhv = h - thv;
            float dc = conf - iou;
            float ovr = 0.5f * (dx * dx + dy * dy + dwv * dwv + dhv * dhv) + 2.5f * dc * dc;
            // class log-softmax over the CS=20 images of this chunk
            int bs = b / CS, cs = b - bs * CS;
            const float* cl = out + (size_t)(bs * CS) * BSTRIDE + (bn * 6 + 5) * CHW + rem;
            float v[CS];
            float m = -1e30f;
#pragma unroll
            for (int c2 = 0; c2 < CS; c2++) { v[c2] = cl[(size_t)c2 * BSTRIDE]; m = fmaxf(m, v[c2]); }
            float s = 0.0f, own = 0.0f;
#pragma unroll
            for (int c2 = 0; c2 < CS; c2++) {
                s += __expf(v[c2] - m);
                if (c2 == cs) own = v[c2];
            }
            contrib = ovr - basel + (m + __logf(s)) - own;
        }
    }

    // block reduction across 4 waves (boxes wave merges via its sred slot)
#pragma unroll
    for (int o = 32; o > 0; o >>= 1) contrib += __shfl_down(contrib, o, 64);
    if (lane == 0) sred[wid] = contrib;
    __syncthreads();
    if (tid == 0) part[b * NCBLK + blockIdx.x] = sred[0] + sred[1] + sred[2] + sred[3];
}

// ---------------------------------------------------------------------------
// Finisher: 1 block x 256. Sums part[1300], computes dmin from dmat[400],
// writes loss[0]. Ordering via kernel boundary (no atomics anywhere).
// ---------------------------------------------------------------------------
__global__ __launch_bounds__(256) void finish_k(const int* __restrict__ ids,
                                                const float* __restrict__ part,
                                                const float* __restrict__ dmat,
                                                float* __restrict__ loss) {
    __shared__ float sred[4];
    __shared__ int scnt[NMETA];
    __shared__ float sdd;
    int tid = threadIdx.x;
    int lane = tid & 63, wid = tid >> 6;

    if (tid < NMETA) {
        int c = 0;
        for (int r = 0; r < DWROWS; r++) c += (ids[r] == tid) ? 1 : 0;
        scnt[tid] = c;
    }
    __syncthreads();
    float dd = 0.0f;
    if (tid < NMETA && scnt[tid] > 0) {
        float dmin = INFINITY;
        bool any = false;
        for (int j = 0; j < NMETA; j++) {
            if (j != tid && scnt[j] > 0) {
                any = true;
                dmin = fminf(dmin, dmat[tid * NMETA + j]);
            }
        }
        dd = any ? dmin : 0.0f;
    }
    if (tid < 64) {
#pragma unroll
        for (int o = 32; o > 0; o >>= 1) dd += __shfl_down(dd, o, 64);
        if (tid == 0) sdd = dd;
    }
    float ps = 0.0f;
    for (int i2 = tid; i2 < NPART; i2 += 256) ps += part[i2];
#pragma unroll
    for (int o = 32; o > 0; o >>= 1) ps += __shfl_down(ps, o, 64);
    if (lane == 0) sred[wid] = ps;
    __syncthreads();
    if (tid == 0) loss[0] = (sred[0] + sred[1] + sred[2] + sred[3]) - sdd;
}

// ---------------------------------------------------------------------------
extern "C" void kernel_launch(void* const* d_in, const int* in_sizes, int n_in,
                              void* d_out, int out_size, void* d_ws, size_t ws_size,
                              hipStream_t stream) {
    const float* output = (const float*)d_in[0];   // (320, 30, 26, 26)
    const float* target = (const float*)d_in[1];   // (16, 20, 250) == (320, 50, 5)
    const float* dw     = (const float*)d_in[2];   // (1, 64, 1024)
    const int*   ids    = (const int*)d_in[3];     // (64,)
    float* loss = (float*)d_out;

    float* part = (float*)d_ws;                    // 1300 loss partials
    float* dmat = part + NPART;                    // 400 pair distances

    dim3 grid(NCBLK, NB + NMETAY);                 // (4, 425): 1280 region + 420 meta
    fused_k<<<grid, 256, 0, stream>>>(output, target, dw, ids, part, dmat);
    finish_k<<<1, 256, 0, stream>>>(ids, part, dmat, loss);
}